// Round 3
// baseline (114.514 us; speedup 1.0000x reference)
//
#include <hip/hip_runtime.h>

// Sinkhorn (loop-never-runs degenerate): out[b] = sum_{i,j} c * exp(-10*c),
// c = (xs_i - ys_j)^2 + (x_i - y_j)^2.  B=8, N=M=4096.
//
// Compute-bound. Key idea: packed-FP32 (v_pk_*_f32) formulation.
//   u = K*c = (K*b_j + K*a_i) + (-2K*vx)*v_j + (-2K*sx)*s_j
//   where a_i = sx^2+vx^2 (row), b_j = s_j^2+v_j^2 (column).
//   sum c*exp(-10c) = (1/K) * sum u * 2^u.
// Per 2 columns: pk_add + 2*pk_fma + 2*v_exp + pk_fma = 4 pk + 2 trans.

typedef float f32x2 __attribute__((ext_vector_type(2)));

constexpr int B_ = 8;
constexpr int N_ = 4096;
constexpr int M_ = 4096;
constexpr int THREADS = 256;
constexpr int ROWS_PER_BLOCK = 8;                        // 512 blocks/batch
constexpr int BLOCKS_PER_BATCH = N_ / ROWS_PER_BLOCK;    // 512
constexpr int TOTAL_BLOCKS = B_ * BLOCKS_PER_BATCH;      // 4096

__global__ __launch_bounds__(THREADS) void sinkhorn_kernel(
    const float* __restrict__ x,  const float* __restrict__ y,
    const float* __restrict__ xs, const float* __restrict__ ys,
    float* __restrict__ out)
{
    const int b  = blockIdx.x >> 9;    // / BLOCKS_PER_BATCH
    const int rb = blockIdx.x & 511;   // % BLOCKS_PER_BATCH
    const int t  = threadIdx.x;

    constexpr float K   = -14.426950408889634f;   // -10 * log2(e)
    constexpr float m2K =  28.853900817779268f;   // -2 * K

    // Row constants: (m2K*sx, m2K*vx, K*(sx^2+vx^2)) per row, staged in LDS.
    __shared__ float4 rowc[ROWS_PER_BLOCK];
    const float* xrow  = x  + (size_t)b * N_ + rb * ROWS_PER_BLOCK;
    const float* xsrow = xs + (size_t)b * N_ + rb * ROWS_PER_BLOCK;
    if (t < ROWS_PER_BLOCK) {
        const float sx = xsrow[t];
        const float vx = xrow[t];
        rowc[t] = make_float4(m2K * sx, m2K * vx, K * (sx * sx + vx * vx), 0.0f);
    }

    // 16 y-columns per thread, register-resident as 8 float2 pairs.
    const float4* yv4 = reinterpret_cast<const float4*>(y  + (size_t)b * M_);
    const float4* ys4 = reinterpret_cast<const float4*>(ys + (size_t)b * M_);
    f32x2 v[8], s[8], bK[8];
#pragma unroll
    for (int k = 0; k < 4; ++k) {
        const float4 a = yv4[k * THREADS + t];
        const float4 g = ys4[k * THREADS + t];
        v[2*k]   = f32x2{a.x, a.y};  v[2*k+1] = f32x2{a.z, a.w};
        s[2*k]   = f32x2{g.x, g.y};  s[2*k+1] = f32x2{g.z, g.w};
    }
#pragma unroll
    for (int k = 0; k < 8; ++k)
        bK[k] = (s[k] * s[k] + v[k] * v[k]) * K;

    __syncthreads();

    f32x2 acc = {0.0f, 0.0f};
#pragma unroll
    for (int r = 0; r < ROWS_PER_BLOCK; ++r) {
        const float4 rc = rowc[r];   // ds_read_b128 broadcast
#pragma unroll
        for (int k = 0; k < 8; ++k) {
            // u = K*c  (4 packed ops: pk_add, pk_fma, pk_fma; acc pk_fma below)
            f32x2 u = (bK[k] + rc.z) + v[k] * rc.y + s[k] * rc.x;
            f32x2 e;
            e.x = __builtin_amdgcn_exp2f(u.x);
            e.y = __builtin_amdgcn_exp2f(u.y);
            acc += u * e;
        }
    }

    // result contribution = (acc.x + acc.y) / K
    float a = (acc.x + acc.y) * (1.0f / K);

    // wave (64-lane) shuffle reduce
#pragma unroll
    for (int off = 32; off > 0; off >>= 1)
        a += __shfl_down(a, off, 64);

    __shared__ float wsum[THREADS / 64];
    const int lane = t & 63, wid = t >> 6;
    if (lane == 0) wsum[wid] = a;
    __syncthreads();
    if (t == 0) {
        float sum = 0.0f;
#pragma unroll
        for (int w = 0; w < THREADS / 64; ++w) sum += wsum[w];
        atomicAdd(&out[b], sum);
    }
}

extern "C" void kernel_launch(void* const* d_in, const int* in_sizes, int n_in,
                              void* d_out, int out_size, void* d_ws, size_t ws_size,
                              hipStream_t stream) {
    const float* x  = (const float*)d_in[0];
    const float* y  = (const float*)d_in[1];
    const float* xs = (const float*)d_in[2];
    const float* ys = (const float*)d_in[3];
    float* out = (float*)d_out;

    // d_out is poisoned 0xAA before every launch — zero it (capture-safe).
    hipMemsetAsync(out, 0, (size_t)out_size * sizeof(float), stream);

    sinkhorn_kernel<<<TOTAL_BLOCKS, THREADS, 0, stream>>>(x, y, xs, ys, out);
}

// Round 4
// 89.684 us; speedup vs baseline: 1.2769x; 1.2769x over previous
//
#include <hip/hip_runtime.h>

// Sinkhorn (loop-never-runs degenerate): out[b] = sum_{i,j} c * exp(-10*c),
// c = (xs_i - ys_j)^2 + (x_i - y_j)^2.  B=8, N=M=4096.
//
// Packed-FP32 (v_pk_*_f32) formulation:
//   u = K*c = (K*b_j + K*a_i) + (-2K*vx)*v_j + (-2K*sx)*s_j
//   a_i = sx^2+vx^2 (row), b_j = s_j^2+v_j^2 (col);  sum c*e^{-10c} = (1/K) sum u*2^u.
// Per 2 columns: pk_add + 2*pk_fma + 2*v_exp + pk_fma = 4 pk + 2 trans.
//
// R3 post-mortem: VGPR_Count=32 proved the compiler was re-loading the
// "register-resident" y-state every row iteration (stall-dominated, VALUBusy 24%).
// __launch_bounds__(256, 4) raises the VGPR cap to 128 so the 48-float y-state
// stays live across the row loop. Occupancy 4 waves/EU — same as measured R3,
// but with a memory-free inner loop.

typedef float f32x2 __attribute__((ext_vector_type(2)));

constexpr int B_ = 8;
constexpr int N_ = 4096;
constexpr int M_ = 4096;
constexpr int THREADS = 256;
constexpr int ROWS_PER_BLOCK = 16;                       // 256 blocks/batch
constexpr int BLOCKS_PER_BATCH = N_ / ROWS_PER_BLOCK;    // 256
constexpr int TOTAL_BLOCKS = B_ * BLOCKS_PER_BATCH;      // 2048 -> 8 blocks/CU demand

__global__ __launch_bounds__(THREADS, 4) void sinkhorn_kernel(
    const float* __restrict__ x,  const float* __restrict__ y,
    const float* __restrict__ xs, const float* __restrict__ ys,
    float* __restrict__ out)
{
    const int b  = blockIdx.x >> 8;    // / BLOCKS_PER_BATCH
    const int rb = blockIdx.x & 255;   // % BLOCKS_PER_BATCH
    const int t  = threadIdx.x;

    constexpr float K   = -14.426950408889634f;   // -10 * log2(e)
    constexpr float m2K =  28.853900817779268f;   // -2 * K

    // Row constants (m2K*sx, m2K*vx, K*(sx^2+vx^2)) staged in LDS once.
    __shared__ float4 rowc[ROWS_PER_BLOCK];
    const float* xrow  = x  + (size_t)b * N_ + rb * ROWS_PER_BLOCK;
    const float* xsrow = xs + (size_t)b * N_ + rb * ROWS_PER_BLOCK;
    if (t < ROWS_PER_BLOCK) {
        const float sx = xsrow[t];
        const float vx = xrow[t];
        rowc[t] = make_float4(m2K * sx, m2K * vx, K * (sx * sx + vx * vx), 0.0f);
    }

    // 16 y-columns per thread, register-resident as 8 f32x2 triples (48 VGPRs).
    const float4* yv4 = reinterpret_cast<const float4*>(y  + (size_t)b * M_);
    const float4* ys4 = reinterpret_cast<const float4*>(ys + (size_t)b * M_);
    f32x2 v[8], s[8], bK[8];
#pragma unroll
    for (int k = 0; k < 4; ++k) {
        const float4 a = yv4[k * THREADS + t];
        const float4 g = ys4[k * THREADS + t];
        v[2*k]   = f32x2{a.x, a.y};  v[2*k+1] = f32x2{a.z, a.w};
        s[2*k]   = f32x2{g.x, g.y};  s[2*k+1] = f32x2{g.z, g.w};
    }
#pragma unroll
    for (int k = 0; k < 8; ++k)
        bK[k] = (s[k] * s[k] + v[k] * v[k]) * K;

    __syncthreads();

    f32x2 acc = {0.0f, 0.0f};
#pragma unroll 2
    for (int r = 0; r < ROWS_PER_BLOCK; ++r) {
        const float4 rc = rowc[r];   // ds_read_b128 broadcast, 16 per thread total
        const f32x2 cx = {rc.x, rc.x};
        const f32x2 cy = {rc.y, rc.y};
        const f32x2 cz = {rc.z, rc.z};
#pragma unroll
        for (int k = 0; k < 8; ++k) {
            f32x2 u = (bK[k] + cz) + v[k] * cy + s[k] * cx;   // 3 pk ops
            f32x2 e;
            e.x = __builtin_amdgcn_exp2f(u.x);
            e.y = __builtin_amdgcn_exp2f(u.y);
            acc += u * e;                                      // 1 pk fma
        }
    }

    // contribution = (acc.x + acc.y) / K
    float a = (acc.x + acc.y) * (1.0f / K);

    // wave (64-lane) shuffle reduce
#pragma unroll
    for (int off = 32; off > 0; off >>= 1)
        a += __shfl_down(a, off, 64);

    __shared__ float wsum[THREADS / 64];
    const int lane = t & 63, wid = t >> 6;
    if (lane == 0) wsum[wid] = a;
    __syncthreads();
    if (t == 0) {
        float sum = 0.0f;
#pragma unroll
        for (int w = 0; w < THREADS / 64; ++w) sum += wsum[w];
        atomicAdd(&out[b], sum);
    }
}

extern "C" void kernel_launch(void* const* d_in, const int* in_sizes, int n_in,
                              void* d_out, int out_size, void* d_ws, size_t ws_size,
                              hipStream_t stream) {
    const float* x  = (const float*)d_in[0];
    const float* y  = (const float*)d_in[1];
    const float* xs = (const float*)d_in[2];
    const float* ys = (const float*)d_in[3];
    float* out = (float*)d_out;

    // d_out is poisoned 0xAA before every launch — zero it (capture-safe).
    hipMemsetAsync(out, 0, (size_t)out_size * sizeof(float), stream);

    sinkhorn_kernel<<<TOTAL_BLOCKS, THREADS, 0, stream>>>(x, y, xs, ys, out);
}